// Round 15
// baseline (264.574 us; speedup 1.0000x reference)
//
#include <hip/hip_runtime.h>
#include <math.h>

typedef __attribute__((ext_vector_type(8))) short short8;
typedef __attribute__((ext_vector_type(4))) float f32x4;
typedef __attribute__((ext_vector_type(4))) unsigned short us4;
typedef __attribute__((ext_vector_type(4))) unsigned int u32x4;
typedef __attribute__((ext_vector_type(4))) int i32x4;
typedef unsigned short u16;
typedef unsigned int u32;

#define LOG2E 1.4426950408889634f
// B=4, S=2048, E=1024, H=16, D=64, M=B*S=8192

static __device__ __forceinline__ u16 f2bf(float f){
  u32 u = __builtin_bit_cast(u32, f);
  u = (u + 0x7FFFu + ((u >> 16) & 1u)) >> 16;   // RTNE
  return (u16)u;
}
// NOTE: v_cvt_pk_bf16_f32 (and __float22bfloat162_rn) is NOT RTNE on gfx950 —
// using it for the P-pack cost 7e-3 absmax (rounds 2 & 5). Keep manual RTNE.
// NOTE2: 2-tile software pipeline (round 8) regressed 173->307us: VGPR spill.
// NOTE3: K direct-from-global (round 11) regressed: unprefetched L2 latency.
// NOTE4: mq=2 + KVBLK=128 half-unroll (round 12) spilled. r7-form only.
// NOTE5: attn converged ~150us across 5 decompositions = plain-HIP structural
// floor (1.79G softmax-elem/us == m214 ladder endpoint). Parked.
// NOTE6 (this round): QKV GEMM ported to 8-phase 256^2 schedule (T3+T4):
// quadrants (0,0),(0,1),(1,1),(1,0); stage P0:T+1.A1, P1-4:T+2.*, P5-7:T+3.*;
// vmcnt(6) at P3/P7 (ledger-derived, matches guide); persistent 256 blocks.

static __device__ __forceinline__ void gload16(const void* g, void* l){
  __builtin_amdgcn_global_load_lds((const __attribute__((address_space(1))) void*)g,
                                   (__attribute__((address_space(3))) void*)l,
                                   16, 0, 0);
}

static __device__ __forceinline__ f32x4 mfma16(short8 a, short8 b, f32x4 c){
  return __builtin_amdgcn_mfma_f32_16x16x32_bf16(a, b, c, 0, 0, 0);
}

// ---------------- RoPE cos/sin table: [s][i], i = 0..31 ----------------
__global__ void rope_tab_k(float* __restrict__ cosT, float* __restrict__ sinT){
  int idx = blockIdx.x * 256 + threadIdx.x;   // 2048*32 = 65536
  int s = idx >> 5, i = idx & 31;
  double th = pow(10000.0, -((double)(2 * i)) / 64.0);
  float ang = (float)s * (float)th;           // fp32 rounding matches reference
  cosT[idx] = (float)cos((double)ang);
  sinT[idx] = (float)sin((double)ang);
}

// ---------------- x fp32 -> bf16 ----------------
__global__ void cvt_x_k(const float* __restrict__ x, u16* __restrict__ xb, int n){
  int i = (blockIdx.x * 256 + threadIdx.x) * 4;
  if (i >= n) return;
  f32x4 v = *(const f32x4*)(x + i);
  us4 o; o[0]=f2bf(v[0]); o[1]=f2bf(v[1]); o[2]=f2bf(v[2]); o[3]=f2bf(v[3]);
  *(us4*)(xb + i) = o;
}

// ---------------- W (k,n) fp32 -> WT (n,k) bf16, 4 matrices ----------------
__global__ void wt_cvt_k(const float* __restrict__ W0, const float* __restrict__ W1,
                         const float* __restrict__ W2, const float* __restrict__ W3,
                         u16* __restrict__ out){
  __shared__ float t[32][33];
  const float* W = (blockIdx.z == 0) ? W0 : (blockIdx.z == 1) ? W1 : (blockIdx.z == 2) ? W2 : W3;
  u16* O = out + (size_t)blockIdx.z * 1024 * 1024;
  int tx = threadIdx.x, ty = threadIdx.y;
  int kb = blockIdx.y * 32, nb = blockIdx.x * 32;
  #pragma unroll
  for (int i = 0; i < 4; i++)
    t[ty + i*8][tx] = W[(size_t)(kb + ty + i*8) * 1024 + nb + tx];
  __syncthreads();
  #pragma unroll
  for (int i = 0; i < 4; i++)
    O[(size_t)(nb + ty + i*8) * 1024 + kb + tx] = f2bf(t[tx][ty + i*8]);
}

// ---------------- 8-phase fused QKV GEMM (256x256 tiles, persistent blocks) --------
// A = xb (8192x1024 bf16), B = WT (per-mode 1024x1024, row = out col).
// 384 tiles: tile = (rowT = t&31)*256 rows x (colT = t>>5): mode = colT>>2, cy = colT&3.
// 256 persistent blocks x 512 thr (8 waves: wm = w>>2, wn = w&3; per-wave 128x64).
// LDS 128KB: Al/Bl[2][256][64], elem-swizzle: col ^= ((row>>2)&1)<<4 (both sides).
// Epilogues fused per mode (RoPE/scatter) as before. Accum order bit-identical.
__global__ __launch_bounds__(512, 2)
void qkv_gemm8_k(const u16* __restrict__ A, const u16* __restrict__ WT,
                 const float* __restrict__ bq, const float* __restrict__ bk,
                 const float* __restrict__ bv,
                 const float* __restrict__ cosT, const float* __restrict__ sinT,
                 u16* __restrict__ Qr, u16* __restrict__ Kr, u16* __restrict__ Vt)
{
  __shared__ __align__(16) u16 Al[2][256][64];
  __shared__ __align__(16) u16 Bl[2][256][64];
  const int tid = threadIdx.x;
  const int w = tid >> 6, lane = tid & 63, g = lane >> 4, c = lane & 15;
  const int wm = w >> 2, wn = w & 3;
  const int l3 = lane >> 3, l7 = lane & 7;
  const int cswz = ((c >> 2) & 1) << 4;        // read-side swizzle (elem units)

#define STAGE_A(KT, H) do{ int kt_ = (KT); if (kt_ <= 15){ \
    _Pragma("unroll") for (int j = 0; j < 2; j++){ \
      int ib = w*16 + j*8; \
      int rT = ((ib>>6)<<7) + (H)*64 + (ib & 63); \
      int row = rT + l3; \
      int ce = (l7*8) ^ (((row>>2)&1) << 4); \
      gload16(A + (size_t)(R0 + row)*1024 + kt_*64 + ce, &Al[kt_&1][rT][0]); \
    }}}while(0)

#define STAGE_B(KT, H) do{ int kt_ = (KT); if (kt_ <= 15){ \
    _Pragma("unroll") for (int j = 0; j < 2; j++){ \
      int ib = w*16 + j*8; \
      int rT = ((ib>>5)<<6) + (H)*32 + (ib & 31); \
      int row = rT + l3; \
      int ce = (l7*8) ^ (((row>>2)&1) << 4); \
      gload16(BT + (size_t)(C0 + row)*1024 + kt_*64 + ce, &Bl[kt_&1][rT][0]); \
    }}}while(0)

#define RD_A(MH, BUF) do{ _Pragma("unroll") for (int mi = 0; mi < 4; mi++) \
    _Pragma("unroll") for (int ki = 0; ki < 2; ki++) \
      af[mi][ki] = *(const short8*)&Al[BUF][wm*128 + (MH)*64 + mi*16 + c][(ki*32 + g*8) ^ cswz]; }while(0)

#define RD_B(DST, NH, BUF) do{ _Pragma("unroll") for (int ni = 0; ni < 2; ni++) \
    _Pragma("unroll") for (int ki = 0; ki < 2; ki++) \
      DST[ni][ki] = *(const short8*)&Bl[BUF][wn*64 + (NH)*32 + ni*16 + c][(ki*32 + g*8) ^ cswz]; }while(0)

#define MM(MH, NH, BSRC) do{ __builtin_amdgcn_s_setprio(1); \
    _Pragma("unroll") for (int ki = 0; ki < 2; ki++) \
      _Pragma("unroll") for (int mi = 0; mi < 4; mi++) \
        _Pragma("unroll") for (int ni = 0; ni < 2; ni++) \
          acc[(MH)*4+mi][(NH)*2+ni] = mfma16(af[mi][ki], BSRC[ni][ki], acc[(MH)*4+mi][(NH)*2+ni]); \
    __builtin_amdgcn_s_setprio(0); }while(0)

#define BAR() do{ asm volatile("" ::: "memory"); __builtin_amdgcn_s_barrier(); asm volatile("" ::: "memory"); }while(0)

  for (int tile = blockIdx.x; tile < 384; tile += 256){
    const int rowT = tile & 31, colT = tile >> 5;
    const int mode = colT >> 2, cy = colT & 3;
    const int R0 = rowT * 256;
    const int C0 = cy * 256;             // within this mode's N=1024
    const u16* BT = WT + (size_t)mode * 1024 * 1024;
    const float* bias = (mode == 0) ? bq : (mode == 1) ? bk : bv;

    f32x4 acc[8][4];
    const f32x4 vz = {0.f, 0.f, 0.f, 0.f};
    #pragma unroll
    for (int m = 0; m < 8; m++)
      #pragma unroll
      for (int n = 0; n < 4; n++) acc[m][n] = vz;

    short8 af[4][2], bf0[2][2], bf1[2][2];

    // prologue: T0.{A0,B0,B1,A1}, T1.{A0,B0,B1}  (order = steady-state stream)
    STAGE_A(0, 0); STAGE_B(0, 0); STAGE_B(0, 1); STAGE_A(0, 1);
    STAGE_A(1, 0); STAGE_B(1, 0); STAGE_B(1, 1);
    asm volatile("s_waitcnt vmcnt(6)" ::: "memory");   // T0 fully landed
    BAR();

    for (int it = 0; it < 8; ++it){
      const int T = it * 2;
      // P0: (mh0,nh0)
      RD_A(0, 0); RD_B(bf0, 0, 0); STAGE_A(T+1, 1);
      BAR(); MM(0, 0, bf0); BAR();
      // P1: (mh0,nh1)
      RD_B(bf1, 1, 0); STAGE_A(T+2, 0);
      BAR(); MM(0, 1, bf1); BAR();
      // P2: (mh1,nh1)
      RD_A(1, 0); STAGE_B(T+2, 0);
      BAR(); MM(1, 1, bf1); BAR();
      // P3: (mh1,nh0) — K-tile boundary
      STAGE_B(T+2, 1);
      BAR(); MM(1, 0, bf0);
      if (it < 7) asm volatile("s_waitcnt vmcnt(6)" ::: "memory");
      else        asm volatile("s_waitcnt vmcnt(0)" ::: "memory");
      BAR();
      // P4: (mh0,nh0) on buf1
      RD_A(0, 1); RD_B(bf0, 0, 1); STAGE_A(T+2, 1);
      BAR(); MM(0, 0, bf0); BAR();
      // P5
      RD_B(bf1, 1, 1); STAGE_A(T+3, 0);
      BAR(); MM(0, 1, bf1); BAR();
      // P6
      RD_A(1, 1); STAGE_B(T+3, 0);
      BAR(); MM(1, 1, bf1); BAR();
      // P7 — K-tile boundary
      STAGE_B(T+3, 1);
      BAR(); MM(1, 0, bf0);
      if (it < 7) asm volatile("s_waitcnt vmcnt(6)" ::: "memory");
      else        asm volatile("s_waitcnt vmcnt(0)" ::: "memory");
      BAR();
    }

    // ---- epilogue ----
    const int h = cy * 4 + wn;
    if (mode == 2){
      #pragma unroll
      for (int n = 0; n < 4; n++){
        int d = n*16 + c;
        float bvv = bias[C0 + wn*64 + n*16 + c];
        #pragma unroll
        for (int m = 0; m < 8; m++){
          int row0 = R0 + wm*128 + m*16 + g*4;
          int b = row0 >> 11, s0 = row0 & 2047;
          us4 pk;
          #pragma unroll
          for (int r = 0; r < 4; r++) pk[r] = f2bf(acc[m][n][r] + bvv);
          *(us4*)&Vt[((size_t)(b*16 + h)*64 + d)*2048 + s0] = pk;
        }
      }
    } else {
      u16* outB = (mode == 0) ? Qr : Kr;
      const float qs = (mode == 0) ? 0.125f : 1.0f;
      float bvv[4];
      #pragma unroll
      for (int n = 0; n < 4; n++) bvv[n] = bias[C0 + wn*64 + n*16 + c];
      #pragma unroll
      for (int m = 0; m < 8; m++){
        int row0 = R0 + wm*128 + m*16 + g*4;
        int b = row0 >> 11;
        #pragma unroll
        for (int r = 0; r < 4; r++){
          int s = (row0 + r) & 2047;
          float v0 = acc[m][0][r] + bvv[0];
          float v1 = acc[m][1][r] + bvv[1];
          float v2 = acc[m][2][r] + bvv[2];
          float v3 = acc[m][3][r] + bvv[3];
          float ca = cosT[s*32 + c],      sa = sinT[s*32 + c];
          float cb = cosT[s*32 + 16 + c], sb = sinT[s*32 + 16 + c];
          float o0 = (v0*ca - v2*sa) * qs, o2 = (v2*ca + v0*sa) * qs;
          float o1 = (v1*cb - v3*sb) * qs, o3 = (v3*cb + v1*sb) * qs;
          size_t base = ((size_t)(b*16 + h)*2048 + s)*64;
          outB[base +  0 + c] = f2bf(o0);
          outB[base + 16 + c] = f2bf(o1);
          outB[base + 32 + c] = f2bf(o2);
          outB[base + 48 + c] = f2bf(o3);
        }
      }
    }
    BAR();   // all waves done with epilogue before next tile's prologue staging
  }
#undef STAGE_A
#undef STAGE_B
#undef RD_A
#undef RD_B
#undef MM
#undef BAR
}

// ---------------- output GEMM (AO x Wo^T + bo -> fp32 out) ----------------
__global__ __launch_bounds__(256, 2)
void out_gemm_k(const u16* __restrict__ A, const u16* __restrict__ BT,
                const float* __restrict__ bias, float* __restrict__ outF)
{
  __shared__ __align__(16) u16 Al[128][64];
  __shared__ __align__(16) u16 Bl[128][64];
  const int tid = threadIdx.x;
  const int w = tid >> 6, lane = tid & 63, g = lane >> 4, c = lane & 15;
  const int wr = w >> 1, wc = w & 1;
  const int R0 = blockIdx.x * 128, C0 = blockIdx.y * 128;

  f32x4 acc[4][4];
  const f32x4 vz = {0.f, 0.f, 0.f, 0.f};
  #pragma unroll
  for (int mi = 0; mi < 4; mi++)
    #pragma unroll
    for (int ni = 0; ni < 4; ni++) acc[mi][ni] = vz;

  const u16* gA[4]; const u16* gB[4]; u16* lA[4]; u16* lB[4];
  #pragma unroll
  for (int i = 0; i < 4; i++){
    int I = w * 4 + i;
    int rr = I * 8 + (lane >> 3), kk = (lane & 7) * 8;
    gA[i] = A  + (size_t)(R0 + rr) * 1024 + kk;
    gB[i] = BT + (size_t)(C0 + rr) * 1024 + kk;
    lA[i] = &Al[I * 8][0];
    lB[i] = &Bl[I * 8][0];
  }

  for (int t = 0; t < 16; ++t){
    const int k0 = t * 64;
    #pragma unroll
    for (int i = 0; i < 4; i++){
      gload16(gA[i] + k0, lA[i]);
      gload16(gB[i] + k0, lB[i]);
    }
    __syncthreads();
    #pragma unroll
    for (int ki = 0; ki < 2; ++ki){
      short8 af[4], bfr[4];
      #pragma unroll
      for (int mi = 0; mi < 4; mi++) af[mi]  = *(const short8*)&Al[wr*64 + mi*16 + c][ki*32 + g*8];
      #pragma unroll
      for (int ni = 0; ni < 4; ni++) bfr[ni] = *(const short8*)&Bl[wc*64 + ni*16 + c][ki*32 + g*8];
      #pragma unroll
      for (int mi = 0; mi < 4; mi++)
        #pragma unroll
        for (int ni = 0; ni < 4; ni++)
          acc[mi][ni] = mfma16(af[mi], bfr[ni], acc[mi][ni]);
    }
    __syncthreads();
  }

  #pragma unroll
  for (int mi = 0; mi < 4; mi++){
    #pragma unroll
    for (int ni = 0; ni < 4; ni++){
      int col = C0 + wc*64 + ni*16 + c;
      float bvv = bias[col];
      int row0 = R0 + wr*64 + mi*16 + g*4;
      #pragma unroll
      for (int r = 0; r < 4; r++)
        outF[(size_t)(row0 + r) * 1024 + col] = acc[mi][ni][r] + bvv;
    }
  }
}

// ---------------- flash attention (8 waves x 32 q-rows, 4-buf ring) ----------------
__global__ __launch_bounds__(512, 4)
void attn_fwd_k(const u16* __restrict__ Q, const u16* __restrict__ K, const u16* __restrict__ V,
                const int* __restrict__ msk, u16* __restrict__ AO)
{
  __shared__ __align__(16) u16 Kl[4][64][64];
  __shared__ __align__(16) u16 Vl[4][64][64];
  __shared__ __align__(8) unsigned char Ml[2048];
  const int tid = threadIdx.x;
  const int w = tid >> 6, lane = tid & 63, g = lane >> 4, c = lane & 15;

  // XCD-aware swizzle (bijective, 512 = 8*64): XCD = lin%8 gets 8 full bh
  const int lin = blockIdx.y * 8 + blockIdx.x;
  const int v_  = (lin & 7) * 64 + (lin >> 3);
  const int bh = v_ >> 3, b = bh >> 4, h = bh & 15;
  const int qw = (v_ & 7) * 256 + w * 32;

  // pack mask row for this b into LDS as u8 (0/1): 512 thr x 4 ints (1 VMEM load)
  {
    const int* mp = msk + b*2048 + tid*4;
    i32x4 a = *(const i32x4*)mp;
    u32 lo = (a[0] ? 1u : 0u) | (a[1] ? 0x100u : 0u) | (a[2] ? 0x10000u : 0u) | (a[3] ? 0x1000000u : 0u);
    *(u32*)&Ml[tid*4] = lo;
  }
  asm volatile("s_waitcnt lgkmcnt(0)" ::: "memory");  // Ml writes drained before first barrier

  // Q B-fragments (4 global loads; over-drained by first vmcnt(4))
  short8 qb[2][2];
  #pragma unroll
  for (int mq = 0; mq < 2; mq++)
    #pragma unroll
    for (int ki = 0; ki < 2; ki++)
      qb[mq][ki] = *(const short8*)&Q[((size_t)bh*2048 + qw + mq*16 + c)*64 + ki*32 + g*8];

  // per-lane staging source (pre-swizzled cols; K rows pi-permuted); 1 K + 1 V load/wave
  const int l3 = lane >> 3, l7 = lane & 7;
  const int scol = (l7 ^ l3) * 8;
  const int s8 = w*8 + l3;                                           // stored row
  const int ps = (s8 & 0x20) | ((s8 & 0x10) >> 2) | ((s8 & 0x0C) << 1) | (s8 & 3); // pi
  const u16* gK = K + ((size_t)bh*2048 + ps)*64 + scol;
  const u16* gV = V + ((size_t)bh*64 + s8)*2048 + scol;

  // prologue: stage tiles 0,1 into bufs 0,1
  gload16(gK,                       &Kl[0][w*8][0]);
  gload16(gV,                       &Vl[0][w*8][0]);
  gload16(gK + (size_t)64*64,       &Kl[1][w*8][0]);
  gload16(gV + (size_t)64,          &Vl[1][w*8][0]);

  f32x4 oacc[2][4];
  float mrun[2], lrun[2];
  const f32x4 vz = {0.f, 0.f, 0.f, 0.f};
  #pragma unroll
  for (int mq = 0; mq < 2; mq++){
    #pragma unroll
    for (int nd = 0; nd < 4; nd++) oacc[mq][nd] = vz;
    mrun[mq] = -1e30f; lrun[mq] = 0.f;
  }

  const int cs0 = (g*8) ^ ((c & 7) << 3);          // swizzled read col, ki=0
  const int cs1 = (32 + g*8) ^ ((c & 7) << 3);     // swizzled read col, ki=1

  for (int t = 0; t < 32; ++t){
    // stage tile t+2 into buf (t+2)&3  (t>=30 over-stage lands in adjacent ws, unused)
    gload16(gK + (size_t)(t+2) * 64 * 64, &Kl[(t+2)&3][w*8][0]);
    gload16(gV + (size_t)(t+2) * 64,      &Vl[(t+2)&3][w*8][0]);
    asm volatile("s_waitcnt vmcnt(4)" ::: "memory");
    __builtin_amdgcn_s_barrier();
    asm volatile("" ::: "memory");

    const u16* Kb = &Kl[t&3][0][0];
    const u16* Vb = &Vl[t&3][0][0];
    const int t0 = t * 64;

    // S^T = K (A) x Q (B)
    f32x4 sacc[4][2];
    #pragma unroll
    for (int nt = 0; nt < 4; nt++){ sacc[nt][0] = vz; sacc[nt][1] = vz; }
    #pragma unroll
    for (int ki = 0; ki < 2; ki++){
      const int cs = ki ? cs1 : cs0;
      short8 ka[4];
      #pragma unroll
      for (int nt = 0; nt < 4; nt++) ka[nt] = *(const short8*)&Kb[(nt*16 + c)*64 + cs];
      __builtin_amdgcn_s_setprio(1);
      #pragma unroll
      for (int nt = 0; nt < 4; nt++)
        #pragma unroll
        for (int mq = 0; mq < 2; mq++)
          sacc[nt][mq] = mfma16(ka[nt], qb[mq][ki], sacc[nt][mq]);
      __builtin_amdgcn_s_setprio(0);
    }

    // mask (u8)
    {
      const u32 mw0 = *(const u32*)&Ml[t0 + 8*g];
      const u32 mw1 = *(const u32*)&Ml[t0 + 8*g + 4];
      const u32 mw2 = *(const u32*)&Ml[t0 + 32 + 8*g];
      const u32 mw3 = *(const u32*)&Ml[t0 + 32 + 8*g + 4];
      if (!__all((mw0 & mw1 & mw2 & mw3) == 0x01010101u)){
        const u32 mw[4] = {mw0, mw1, mw2, mw3};
        #pragma unroll
        for (int nt = 0; nt < 4; nt++)
          #pragma unroll
          for (int r = 0; r < 4; r++)
            if (((mw[nt] >> (8*r)) & 0xFFu) == 0){ sacc[nt][0][r] = -1e9f; sacc[nt][1][r] = -1e9f; }
      }
    }

    // tile max (tree) per mq
    float pm[2];
    #pragma unroll
    for (int mq = 0; mq < 2; mq++){
      float a0 = fmaxf(fmaxf(sacc[0][mq][0], sacc[0][mq][1]), fmaxf(sacc[0][mq][2], sacc[0][mq][3]));
      float a1 = fmaxf(fmaxf(sacc[1][mq][0], sacc[1][mq][1]), fmaxf(sacc[1][mq][2], sacc[1][mq][3]));
      float a2 = fmaxf(fmaxf(sacc[2][mq][0], sacc[2][mq][1]), fmaxf(sacc[2][mq][2], sacc[2][mq][3]));
      float a3 = fmaxf(fmaxf(sacc[3][mq][0], sacc[3][mq][1]), fmaxf(sacc[3][mq][2], sacc[3][mq][3]));
      float mm = fmaxf(fmaxf(a0, a1), fmaxf(a2, a3));
      mm = fmaxf(mm, __shfl_xor(mm, 16, 64));
      mm = fmaxf(mm, __shfl_xor(mm, 32, 64));
      pm[mq] = mm;
    }

    // defer-max rescale (exact skip when pm<=mrun)
    if (__any((pm[0] > mrun[0] + 8.f) | (pm[1] > mrun[1] + 8.f))){
      float al[2];
      #pragma unroll
      for (int mq = 0; mq < 2; mq++){
        float mn = fmaxf(mrun[mq], pm[mq]);
        al[mq] = exp2f((mrun[mq] - mn) * LOG2E);
        mrun[mq] = mn;
        lrun[mq] *= al[mq];
      }
      #pragma unroll
      for (int mq = 0; mq < 2; mq++){
        float b0 = __shfl(al[mq], g*4 + 0, 64);
        float b1 = __shfl(al[mq], g*4 + 1, 64);
        float b2 = __shfl(al[mq], g*4 + 2, 64);
        float b3 = __shfl(al[mq], g*4 + 3, 64);
        #pragma unroll
        for (int nd = 0; nd < 4; nd++){
          oacc[mq][nd][0] *= b0; oacc[mq][nd][1] *= b1;
          oacc[mq][nd][2] *= b2; oacc[mq][nd][3] *= b3;
        }
      }
    }

    // P = exp2((s-m)*log2e): RTNE for PV, tree-sum unrounded into per-lane l
    short8 pa[2][2];
    #pragma unroll
    for (int mq = 0; mq < 2; mq++){
      const float nm = -mrun[mq] * LOG2E;
      float p[16]; u32 rb[16];
      #pragma unroll
      for (int nt = 0; nt < 4; nt++)
        #pragma unroll
        for (int r = 0; r < 4; r++){
          float pp = exp2f(fmaf(sacc[nt][mq][r], LOG2E, nm));
          p[nt*4 + r] = pp;
          u32 u = __builtin_bit_cast(u32, pp);
          rb[nt*4 + r] = u + 0x7FFFu + ((u >> 16) & 1u);   // RTNE in bytes 2,3
        }
      float s0 = (p[0] + p[1]) + (p[2] + p[3]);
      float s1 = (p[4] + p[5]) + (p[6] + p[7]);
      float s2 = (p[8] + p[9]) + (p[10] + p[11]);
      float s3 = (p[12] + p[13]) + (p[14] + p[15]);
      lrun[mq] += (s0 + s1) + (s2 + s3);
      u32x4 q0 = { __builtin_amdgcn_perm(rb[1],  rb[0],  0x07060302u),
                   __builtin_amdgcn_perm(rb[3],  rb[2],  0x07060302u),
                   __builtin_amdgcn_perm(rb[5],  rb[4],  0x07060302u),
                   __builtin_amdgcn_perm(rb[7],  rb[6],  0x07060302u) };
      u32x4 q1 = { __builtin_amdgcn_perm(rb[9],  rb[8],  0x07060302u),
                   __builtin_amdgcn_perm(rb[11], rb[10], 0x07060302u),
                   __builtin_amdgcn_perm(rb[13], rb[12], 0x07060302u),
                   __builtin_amdgcn_perm(rb[15], rb[14], 0x07060302u) };
      pa[mq][0] = __builtin_bit_cast(short8, q0);
      pa[mq][1] = __builtin_bit_cast(short8, q1);
    }

    // O += P (A) x V (B)
    #pragma unroll
    for (int ki = 0; ki < 2; ki++){
      const int cs = ki ? cs1 : cs0;
      short8 va[4];
      #pragma unroll
      for (int nd = 0; nd < 4; nd++) va[nd] = *(const short8*)&Vb[(nd*16 + c)*64 + cs];
      __builtin_amdgcn_s_setprio(1);
      #pragma unroll
      for (int mq = 0; mq < 2; mq++)
        #pragma unroll
        for (int nd = 0; nd < 4; nd++)
          oacc[mq][nd] = mfma16(pa[mq][ki], va[nd], oacc[mq][nd]);
      __builtin_amdgcn_s_setprio(0);
    }
  }

  // epilogue
  #pragma unroll
  for (int mq = 0; mq < 2; mq++){
    lrun[mq] += __shfl_xor(lrun[mq], 16, 64);
    lrun[mq] += __shfl_xor(lrun[mq], 32, 64);
    #pragma unroll
    for (int r = 0; r < 4; r++){
      float li = __shfl(lrun[mq], g*4 + r, 64);
      float inv = 1.0f / li;
      int q = qw + mq*16 + g*4 + r;
      size_t base = ((size_t)b*2048 + q)*1024 + h*64;
      #pragma unroll
      for (int nd = 0; nd < 4; nd++)
        AO[base + nd*16 + c] = f2bf(oacc[mq][nd][r] * inv);
    }
  }
}

extern "C" void kernel_launch(void* const* d_in, const int* in_sizes, int n_in,
                              void* d_out, int out_size, void* d_ws, size_t ws_size,
                              hipStream_t stream)
{
  const float* x  = (const float*)d_in[0];
  const int* mask = (const int*)d_in[1];
  const float* Wq = (const float*)d_in[2];
  const float* bq = (const float*)d_in[3];
  const float* Wk = (const float*)d_in[4];
  const float* bk = (const float*)d_in[5];
  const float* Wv = (const float*)d_in[6];
  const float* bv = (const float*)d_in[7];
  const float* Wo = (const float*)d_in[8];
  const float* bo = (const float*)d_in[9];
  float* out = (float*)d_out;
  (void)in_sizes; (void)n_in; (void)out_size; (void)ws_size;

  char* ws = (char*)d_ws;
  size_t off = 0;
  auto alloc = [&](size_t bytes){ void* p = ws + off; off += (bytes + 255) & ~(size_t)255; return p; };
  u16* xb    = (u16*)alloc((size_t)8192 * 1024 * 2);
  u16* WT    = (u16*)alloc((size_t)4 * 1024 * 1024 * 2);
  float* cosT = (float*)alloc((size_t)2048 * 32 * 4);
  float* sinT = (float*)alloc((size_t)2048 * 32 * 4);
  u16* Qr    = (u16*)alloc((size_t)8192 * 1024 * 2);
  u16* Kr    = (u16*)alloc((size_t)8192 * 1024 * 2);
  u16* Vt    = (u16*)alloc((size_t)8192 * 1024 * 2);
  u16* AO    = (u16*)alloc((size_t)8192 * 1024 * 2);

  rope_tab_k<<<dim3(256), dim3(256), 0, stream>>>(cosT, sinT);
  cvt_x_k<<<dim3(8192), dim3(256), 0, stream>>>(x, xb, 8192 * 1024);
  wt_cvt_k<<<dim3(32, 32, 4), dim3(32, 8), 0, stream>>>(Wq, Wk, Wv, Wo, WT);

  qkv_gemm8_k<<<dim3(256), dim3(512), 0, stream>>>(xb, WT, bq, bk, bv, cosT, sinT, Qr, Kr, Vt);

  attn_fwd_k<<<dim3(8, 64), dim3(512), 0, stream>>>(Qr, Kr, Vt, mask, AO);

  out_gemm_k<<<dim3(64, 8), dim3(256), 0, stream>>>(AO, WT + 3*1024*1024, bo, out);
}

// Round 16
// 242.902 us; speedup vs baseline: 1.0892x; 1.0892x over previous
//
#include <hip/hip_runtime.h>
#include <math.h>

typedef __attribute__((ext_vector_type(8))) short short8;
typedef __attribute__((ext_vector_type(4))) float f32x4;
typedef __attribute__((ext_vector_type(4))) unsigned short us4;
typedef __attribute__((ext_vector_type(4))) unsigned int u32x4;
typedef __attribute__((ext_vector_type(4))) int i32x4;
typedef unsigned short u16;
typedef unsigned int u32;

#define LOG2E 1.4426950408889634f
// B=4, S=2048, E=1024, H=16, D=64, M=B*S=8192

static __device__ __forceinline__ u16 f2bf(float f){
  u32 u = __builtin_bit_cast(u32, f);
  u = (u + 0x7FFFu + ((u >> 16) & 1u)) >> 16;   // RTNE
  return (u16)u;
}
// NOTE: v_cvt_pk_bf16_f32 (and __float22bfloat162_rn) is NOT RTNE on gfx950 —
// using it for the P-pack cost 7e-3 absmax (rounds 2 & 5). Keep manual RTNE.
// NOTE2: 2-tile software pipeline (round 8) regressed: VGPR spill.
// NOTE3: K direct-from-global (round 11) regressed: unprefetched L2 latency.
// NOTE4: mq=2 + KVBLK=128 half-unroll (round 12) spilled. r7-form only.
// NOTE5: attn converged ~150us across 5 decompositions = plain-HIP structural
// floor (1.79G softmax-elem/us == m214 ladder endpoint). Parked.
// NOTE6: 8-phase 256^2 QKV port (round 15) regressed 56->78us: 384 tiles on
// 256 persistent blocks = 2-pass utilization loss + 128KB LDS -> 1 block/CU
// exposes all 16 barriers/K-tile. m97-structure fused QKV is the right
// operating point at K=1024.

static __device__ __forceinline__ void gload16(const void* g, void* l){
  __builtin_amdgcn_global_load_lds((const __attribute__((address_space(1))) void*)g,
                                   (__attribute__((address_space(3))) void*)l,
                                   16, 0, 0);
}

static __device__ __forceinline__ f32x4 mfma16(short8 a, short8 b, f32x4 c){
  return __builtin_amdgcn_mfma_f32_16x16x32_bf16(a, b, c, 0, 0, 0);
}

// ---------------- RoPE cos/sin table: [s][i], i = 0..31 ----------------
__global__ void rope_tab_k(float* __restrict__ cosT, float* __restrict__ sinT){
  int idx = blockIdx.x * 256 + threadIdx.x;   // 2048*32 = 65536
  int s = idx >> 5, i = idx & 31;
  double th = pow(10000.0, -((double)(2 * i)) / 64.0);
  float ang = (float)s * (float)th;           // fp32 rounding matches reference
  cosT[idx] = (float)cos((double)ang);
  sinT[idx] = (float)sin((double)ang);
}

// ---------------- x fp32 -> bf16 ----------------
__global__ void cvt_x_k(const float* __restrict__ x, u16* __restrict__ xb, int n){
  int i = (blockIdx.x * 256 + threadIdx.x) * 4;
  if (i >= n) return;
  f32x4 v = *(const f32x4*)(x + i);
  us4 o; o[0]=f2bf(v[0]); o[1]=f2bf(v[1]); o[2]=f2bf(v[2]); o[3]=f2bf(v[3]);
  *(us4*)(xb + i) = o;
}

// ---------------- W (k,n) fp32 -> WT (n,k) bf16, 4 matrices ----------------
__global__ void wt_cvt_k(const float* __restrict__ W0, const float* __restrict__ W1,
                         const float* __restrict__ W2, const float* __restrict__ W3,
                         u16* __restrict__ out){
  __shared__ float t[32][33];
  const float* W = (blockIdx.z == 0) ? W0 : (blockIdx.z == 1) ? W1 : (blockIdx.z == 2) ? W2 : W3;
  u16* O = out + (size_t)blockIdx.z * 1024 * 1024;
  int tx = threadIdx.x, ty = threadIdx.y;
  int kb = blockIdx.y * 32, nb = blockIdx.x * 32;
  #pragma unroll
  for (int i = 0; i < 4; i++)
    t[ty + i*8][tx] = W[(size_t)(kb + ty + i*8) * 1024 + nb + tx];
  __syncthreads();
  #pragma unroll
  for (int i = 0; i < 4; i++)
    O[(size_t)(nb + ty + i*8) * 1024 + kb + tx] = f2bf(t[tx][ty + i*8]);
}

// ---------------- fused QKV GEMM 8192x1024x1024 bf16 MFMA ----------------
__global__ __launch_bounds__(256, 2)
void qkv_gemm_k(const u16* __restrict__ A, const u16* __restrict__ WT,
                const float* __restrict__ bq, const float* __restrict__ bk,
                const float* __restrict__ bv,
                const float* __restrict__ cosT, const float* __restrict__ sinT,
                u16* __restrict__ Qr, u16* __restrict__ Kr, u16* __restrict__ Vt)
{
  __shared__ __align__(16) u16 Al[128][64];
  __shared__ __align__(16) u16 Bl[128][64];
  const int mode = blockIdx.y >> 3;
  const int cy   = blockIdx.y & 7;
  const u16* BT = WT + (size_t)mode * 1024 * 1024;
  const float* bias = (mode == 0) ? bq : (mode == 1) ? bk : bv;
  u16* outB = (mode == 0) ? Qr : (mode == 1) ? Kr : Vt;

  const int tid = threadIdx.x;
  const int w = tid >> 6, lane = tid & 63, g = lane >> 4, c = lane & 15;
  const int wr = w >> 1, wc = w & 1;
  const int R0 = blockIdx.x * 128, C0 = cy * 128;

  f32x4 acc[4][4];
  const f32x4 vz = {0.f, 0.f, 0.f, 0.f};
  #pragma unroll
  for (int mi = 0; mi < 4; mi++)
    #pragma unroll
    for (int ni = 0; ni < 4; ni++) acc[mi][ni] = vz;

  const u16* gA[4]; const u16* gB[4]; u16* lA[4]; u16* lB[4];
  #pragma unroll
  for (int i = 0; i < 4; i++){
    int I = w * 4 + i;
    int rr = I * 8 + (lane >> 3), kk = (lane & 7) * 8;
    gA[i] = A  + (size_t)(R0 + rr) * 1024 + kk;
    gB[i] = BT + (size_t)(C0 + rr) * 1024 + kk;
    lA[i] = &Al[I * 8][0];
    lB[i] = &Bl[I * 8][0];
  }

  for (int t = 0; t < 16; ++t){
    const int k0 = t * 64;
    #pragma unroll
    for (int i = 0; i < 4; i++){
      gload16(gA[i] + k0, lA[i]);
      gload16(gB[i] + k0, lB[i]);
    }
    __syncthreads();
    #pragma unroll
    for (int ki = 0; ki < 2; ++ki){
      short8 af[4], bfr[4];
      #pragma unroll
      for (int mi = 0; mi < 4; mi++) af[mi]  = *(const short8*)&Al[wr*64 + mi*16 + c][ki*32 + g*8];
      #pragma unroll
      for (int ni = 0; ni < 4; ni++) bfr[ni] = *(const short8*)&Bl[wc*64 + ni*16 + c][ki*32 + g*8];
      #pragma unroll
      for (int mi = 0; mi < 4; mi++)
        #pragma unroll
        for (int ni = 0; ni < 4; ni++)
          acc[mi][ni] = mfma16(af[mi], bfr[ni], acc[mi][ni]);
    }
    __syncthreads();
  }

  if (mode == 2){
    int h = cy * 2 + wc;
    #pragma unroll
    for (int ni = 0; ni < 4; ni++){
      int col = C0 + wc*64 + ni*16 + c;
      int d = ni*16 + c;
      float bvv = bias[col];
      #pragma unroll
      for (int mi = 0; mi < 4; mi++){
        int row0 = R0 + wr*64 + mi*16 + g*4;
        int b = row0 >> 11, s0 = row0 & 2047;
        us4 pk;
        #pragma unroll
        for (int r = 0; r < 4; r++) pk[r] = f2bf(acc[mi][ni][r] + bvv);
        *(us4*)&outB[((size_t)(b*16 + h)*64 + d)*2048 + s0] = pk;
      }
    }
  } else {
    int h = cy * 2 + wc;
    const float qs = (mode == 0) ? 0.125f : 1.0f;
    float bvv[4];
    #pragma unroll
    for (int ni = 0; ni < 4; ni++) bvv[ni] = bias[C0 + wc*64 + ni*16 + c];
    #pragma unroll
    for (int mi = 0; mi < 4; mi++){
      int row0 = R0 + wr*64 + mi*16 + g*4;
      int b = row0 >> 11;
      #pragma unroll
      for (int r = 0; r < 4; r++){
        int s = (row0 + r) & 2047;
        float v0 = acc[mi][0][r] + bvv[0];
        float v1 = acc[mi][1][r] + bvv[1];
        float v2 = acc[mi][2][r] + bvv[2];
        float v3 = acc[mi][3][r] + bvv[3];
        float ca = cosT[s*32 + c],      sa = sinT[s*32 + c];
        float cb = cosT[s*32 + 16 + c], sb = sinT[s*32 + 16 + c];
        float o0 = (v0*ca - v2*sa) * qs, o2 = (v2*ca + v0*sa) * qs;
        float o1 = (v1*cb - v3*sb) * qs, o3 = (v3*cb + v1*sb) * qs;
        size_t base = ((size_t)(b*16 + h)*2048 + s)*64;
        outB[base +  0 + c] = f2bf(o0);
        outB[base + 16 + c] = f2bf(o1);
        outB[base + 32 + c] = f2bf(o2);
        outB[base + 48 + c] = f2bf(o3);
      }
    }
  }
}

// ---------------- output GEMM (AO x Wo^T + bo -> fp32 out) ----------------
__global__ __launch_bounds__(256, 2)
void out_gemm_k(const u16* __restrict__ A, const u16* __restrict__ BT,
                const float* __restrict__ bias, float* __restrict__ outF)
{
  __shared__ __align__(16) u16 Al[128][64];
  __shared__ __align__(16) u16 Bl[128][64];
  const int tid = threadIdx.x;
  const int w = tid >> 6, lane = tid & 63, g = lane >> 4, c = lane & 15;
  const int wr = w >> 1, wc = w & 1;
  const int R0 = blockIdx.x * 128, C0 = blockIdx.y * 128;

  f32x4 acc[4][4];
  const f32x4 vz = {0.f, 0.f, 0.f, 0.f};
  #pragma unroll
  for (int mi = 0; mi < 4; mi++)
    #pragma unroll
    for (int ni = 0; ni < 4; ni++) acc[mi][ni] = vz;

  const u16* gA[4]; const u16* gB[4]; u16* lA[4]; u16* lB[4];
  #pragma unroll
  for (int i = 0; i < 4; i++){
    int I = w * 4 + i;
    int rr = I * 8 + (lane >> 3), kk = (lane & 7) * 8;
    gA[i] = A  + (size_t)(R0 + rr) * 1024 + kk;
    gB[i] = BT + (size_t)(C0 + rr) * 1024 + kk;
    lA[i] = &Al[I * 8][0];
    lB[i] = &Bl[I * 8][0];
  }

  for (int t = 0; t < 16; ++t){
    const int k0 = t * 64;
    #pragma unroll
    for (int i = 0; i < 4; i++){
      gload16(gA[i] + k0, lA[i]);
      gload16(gB[i] + k0, lB[i]);
    }
    __syncthreads();
    #pragma unroll
    for (int ki = 0; ki < 2; ++ki){
      short8 af[4], bfr[4];
      #pragma unroll
      for (int mi = 0; mi < 4; mi++) af[mi]  = *(const short8*)&Al[wr*64 + mi*16 + c][ki*32 + g*8];
      #pragma unroll
      for (int ni = 0; ni < 4; ni++) bfr[ni] = *(const short8*)&Bl[wc*64 + ni*16 + c][ki*32 + g*8];
      #pragma unroll
      for (int mi = 0; mi < 4; mi++)
        #pragma unroll
        for (int ni = 0; ni < 4; ni++)
          acc[mi][ni] = mfma16(af[mi], bfr[ni], acc[mi][ni]);
    }
    __syncthreads();
  }

  #pragma unroll
  for (int mi = 0; mi < 4; mi++){
    #pragma unroll
    for (int ni = 0; ni < 4; ni++){
      int col = C0 + wc*64 + ni*16 + c;
      float bvv = bias[col];
      int row0 = R0 + wr*64 + mi*16 + g*4;
      #pragma unroll
      for (int r = 0; r < 4; r++)
        outF[(size_t)(row0 + r) * 1024 + col] = acc[mi][ni][r] + bvv;
    }
  }
}

// ---------------- flash attention (8 waves x 32 q-rows, 4-buf ring) ----------------
// Q,K: (b,h,s,d) bf16 (Q pre-scaled by 0.125).  V: (b,h,d,s) bf16.
// out AO: (b,s,h,d) bf16.  512 threads = 8 waves, 32 q-rows each (256/block).
// mq=2 r7-form body, 4-buffer LDS ring, 2-deep prefetch, ONE barrier per tile,
// counted vmcnt(4), setprio around MFMA clusters.
__global__ __launch_bounds__(512, 4)
void attn_fwd_k(const u16* __restrict__ Q, const u16* __restrict__ K, const u16* __restrict__ V,
                const int* __restrict__ msk, u16* __restrict__ AO)
{
  __shared__ __align__(16) u16 Kl[4][64][64];
  __shared__ __align__(16) u16 Vl[4][64][64];
  __shared__ __align__(8) unsigned char Ml[2048];
  const int tid = threadIdx.x;
  const int w = tid >> 6, lane = tid & 63, g = lane >> 4, c = lane & 15;

  // XCD-aware swizzle (bijective, 512 = 8*64): XCD = lin%8 gets 8 full bh
  const int lin = blockIdx.y * 8 + blockIdx.x;
  const int v_  = (lin & 7) * 64 + (lin >> 3);
  const int bh = v_ >> 3, b = bh >> 4, h = bh & 15;
  const int qw = (v_ & 7) * 256 + w * 32;

  // pack mask row for this b into LDS as u8 (0/1): 512 thr x 4 ints (1 VMEM load)
  {
    const int* mp = msk + b*2048 + tid*4;
    i32x4 a = *(const i32x4*)mp;
    u32 lo = (a[0] ? 1u : 0u) | (a[1] ? 0x100u : 0u) | (a[2] ? 0x10000u : 0u) | (a[3] ? 0x1000000u : 0u);
    *(u32*)&Ml[tid*4] = lo;
  }
  asm volatile("s_waitcnt lgkmcnt(0)" ::: "memory");  // Ml writes drained before first barrier

  // Q B-fragments (4 global loads; over-drained by first vmcnt(4))
  short8 qb[2][2];
  #pragma unroll
  for (int mq = 0; mq < 2; mq++)
    #pragma unroll
    for (int ki = 0; ki < 2; ki++)
      qb[mq][ki] = *(const short8*)&Q[((size_t)bh*2048 + qw + mq*16 + c)*64 + ki*32 + g*8];

  // per-lane staging source (pre-swizzled cols; K rows pi-permuted); 1 K + 1 V load/wave
  const int l3 = lane >> 3, l7 = lane & 7;
  const int scol = (l7 ^ l3) * 8;
  const int s8 = w*8 + l3;                                           // stored row
  const int ps = (s8 & 0x20) | ((s8 & 0x10) >> 2) | ((s8 & 0x0C) << 1) | (s8 & 3); // pi
  const u16* gK = K + ((size_t)bh*2048 + ps)*64 + scol;
  const u16* gV = V + ((size_t)bh*64 + s8)*2048 + scol;

  // prologue: stage tiles 0,1 into bufs 0,1
  gload16(gK,                       &Kl[0][w*8][0]);
  gload16(gV,                       &Vl[0][w*8][0]);
  gload16(gK + (size_t)64*64,       &Kl[1][w*8][0]);
  gload16(gV + (size_t)64,          &Vl[1][w*8][0]);

  f32x4 oacc[2][4];
  float mrun[2], lrun[2];
  const f32x4 vz = {0.f, 0.f, 0.f, 0.f};
  #pragma unroll
  for (int mq = 0; mq < 2; mq++){
    #pragma unroll
    for (int nd = 0; nd < 4; nd++) oacc[mq][nd] = vz;
    mrun[mq] = -1e30f; lrun[mq] = 0.f;
  }

  const int cs0 = (g*8) ^ ((c & 7) << 3);          // swizzled read col, ki=0
  const int cs1 = (32 + g*8) ^ ((c & 7) << 3);     // swizzled read col, ki=1

  for (int t = 0; t < 32; ++t){
    // stage tile t+2 into buf (t+2)&3  (t>=30 over-stage lands in adjacent ws, unused)
    gload16(gK + (size_t)(t+2) * 64 * 64, &Kl[(t+2)&3][w*8][0]);
    gload16(gV + (size_t)(t+2) * 64,      &Vl[(t+2)&3][w*8][0]);
    asm volatile("s_waitcnt vmcnt(4)" ::: "memory");
    __builtin_amdgcn_s_barrier();
    asm volatile("" ::: "memory");

    const u16* Kb = &Kl[t&3][0][0];
    const u16* Vb = &Vl[t&3][0][0];
    const int t0 = t * 64;

    // S^T = K (A) x Q (B)
    f32x4 sacc[4][2];
    #pragma unroll
    for (int nt = 0; nt < 4; nt++){ sacc[nt][0] = vz; sacc[nt][1] = vz; }
    #pragma unroll
    for (int ki = 0; ki < 2; ki++){
      const int cs = ki ? cs1 : cs0;
      short8 ka[4];
      #pragma unroll
      for (int nt = 0; nt < 4; nt++) ka[nt] = *(const short8*)&Kb[(nt*16 + c)*64 + cs];
      __builtin_amdgcn_s_setprio(1);
      #pragma unroll
      for (int nt = 0; nt < 4; nt++)
        #pragma unroll
        for (int mq = 0; mq < 2; mq++)
          sacc[nt][mq] = mfma16(ka[nt], qb[mq][ki], sacc[nt][mq]);
      __builtin_amdgcn_s_setprio(0);
    }

    // mask (u8)
    {
      const u32 mw0 = *(const u32*)&Ml[t0 + 8*g];
      const u32 mw1 = *(const u32*)&Ml[t0 + 8*g + 4];
      const u32 mw2 = *(const u32*)&Ml[t0 + 32 + 8*g];
      const u32 mw3 = *(const u32*)&Ml[t0 + 32 + 8*g + 4];
      if (!__all((mw0 & mw1 & mw2 & mw3) == 0x01010101u)){
        const u32 mw[4] = {mw0, mw1, mw2, mw3};
        #pragma unroll
        for (int nt = 0; nt < 4; nt++)
          #pragma unroll
          for (int r = 0; r < 4; r++)
            if (((mw[nt] >> (8*r)) & 0xFFu) == 0){ sacc[nt][0][r] = -1e9f; sacc[nt][1][r] = -1e9f; }
      }
    }

    // tile max (tree) per mq
    float pm[2];
    #pragma unroll
    for (int mq = 0; mq < 2; mq++){
      float a0 = fmaxf(fmaxf(sacc[0][mq][0], sacc[0][mq][1]), fmaxf(sacc[0][mq][2], sacc[0][mq][3]));
      float a1 = fmaxf(fmaxf(sacc[1][mq][0], sacc[1][mq][1]), fmaxf(sacc[1][mq][2], sacc[1][mq][3]));
      float a2 = fmaxf(fmaxf(sacc[2][mq][0], sacc[2][mq][1]), fmaxf(sacc[2][mq][2], sacc[2][mq][3]));
      float a3 = fmaxf(fmaxf(sacc[3][mq][0], sacc[3][mq][1]), fmaxf(sacc[3][mq][2], sacc[3][mq][3]));
      float mm = fmaxf(fmaxf(a0, a1), fmaxf(a2, a3));
      mm = fmaxf(mm, __shfl_xor(mm, 16, 64));
      mm = fmaxf(mm, __shfl_xor(mm, 32, 64));
      pm[mq] = mm;
    }

    // defer-max rescale (exact skip when pm<=mrun)
    if (__any((pm[0] > mrun[0] + 8.f) | (pm[1] > mrun[1] + 8.f))){
      float al[2];
      #pragma unroll
      for (int mq = 0; mq < 2; mq++){
        float mn = fmaxf(mrun[mq], pm[mq]);
        al[mq] = exp2f((mrun[mq] - mn) * LOG2E);
        mrun[mq] = mn;
        lrun[mq] *= al[mq];
      }
      #pragma unroll
      for (int mq = 0; mq < 2; mq++){
        float b0 = __shfl(al[mq], g*4 + 0, 64);
        float b1 = __shfl(al[mq], g*4 + 1, 64);
        float b2 = __shfl(al[mq], g*4 + 2, 64);
        float b3 = __shfl(al[mq], g*4 + 3, 64);
        #pragma unroll
        for (int nd = 0; nd < 4; nd++){
          oacc[mq][nd][0] *= b0; oacc[mq][nd][1] *= b1;
          oacc[mq][nd][2] *= b2; oacc[mq][nd][3] *= b3;
        }
      }
    }

    // P = exp2((s-m)*log2e): RTNE for PV, tree-sum unrounded into per-lane l
    short8 pa[2][2];
    #pragma unroll
    for (int mq = 0; mq < 2; mq++){
      const float nm = -mrun[mq] * LOG2E;
      float p[16]; u32 rb[16];
      #pragma unroll
      for (int nt = 0; nt < 4; nt++)
        #pragma unroll
        for (int r = 0; r < 4; r++){
          float pp = exp2f(fmaf(sacc[nt][mq][r], LOG2E, nm));
          p[nt*4 + r] = pp;
          u32 u = __builtin_bit_cast(u32, pp);
          rb[nt*4 + r] = u + 0x7FFFu + ((u >> 16) & 1u);   // RTNE in bytes 2,3
        }
      float s0 = (p[0] + p[1]) + (p[2] + p[3]);
      float s1 = (p[4] + p[5]) + (p[6] + p[7]);
      float s2 = (p[8] + p[9]) + (p[10] + p[11]);
      float s3 = (p[12] + p[13]) + (p[14] + p[15]);
      lrun[mq] += (s0 + s1) + (s2 + s3);
      u32x4 q0 = { __builtin_amdgcn_perm(rb[1],  rb[0],  0x07060302u),
                   __builtin_amdgcn_perm(rb[3],  rb[2],  0x07060302u),
                   __builtin_amdgcn_perm(rb[5],  rb[4],  0x07060302u),
                   __builtin_amdgcn_perm(rb[7],  rb[6],  0x07060302u) };
      u32x4 q1 = { __builtin_amdgcn_perm(rb[9],  rb[8],  0x07060302u),
                   __builtin_amdgcn_perm(rb[11], rb[10], 0x07060302u),
                   __builtin_amdgcn_perm(rb[13], rb[12], 0x07060302u),
                   __builtin_amdgcn_perm(rb[15], rb[14], 0x07060302u) };
      pa[mq][0] = __builtin_bit_cast(short8, q0);
      pa[mq][1] = __builtin_bit_cast(short8, q1);
    }

    // O += P (A) x V (B)
    #pragma unroll
    for (int ki = 0; ki < 2; ki++){
      const int cs = ki ? cs1 : cs0;
      short8 va[4];
      #pragma unroll
      for (int nd = 0; nd < 4; nd++) va[nd] = *(const short8*)&Vb[(nd*16 + c)*64 + cs];
      __builtin_amdgcn_s_setprio(1);
      #pragma unroll
      for (int mq = 0; mq < 2; mq++)
        #pragma unroll
        for (int nd = 0; nd < 4; nd++)
          oacc[mq][nd] = mfma16(pa[mq][ki], va[nd], oacc[mq][nd]);
      __builtin_amdgcn_s_setprio(0);
    }
    // no end-of-tile barrier: 4-buf ring makes next stage target safe (skew < 2)
  }

  // epilogue: reduce per-lane l partials once; O rows q = qw + mq*16 + 4g + r
  #pragma unroll
  for (int mq = 0; mq < 2; mq++){
    lrun[mq] += __shfl_xor(lrun[mq], 16, 64);
    lrun[mq] += __shfl_xor(lrun[mq], 32, 64);
    #pragma unroll
    for (int r = 0; r < 4; r++){
      float li = __shfl(lrun[mq], g*4 + r, 64);
      float inv = 1.0f / li;
      int q = qw + mq*16 + g*4 + r;
      size_t base = ((size_t)b*2048 + q)*1024 + h*64;
      #pragma unroll
      for (int nd = 0; nd < 4; nd++)
        AO[base + nd*16 + c] = f2bf(oacc[mq][nd][r] * inv);
    }
  }
}

extern "C" void kernel_launch(void* const* d_in, const int* in_sizes, int n_in,
                              void* d_out, int out_size, void* d_ws, size_t ws_size,
                              hipStream_t stream)
{
  const float* x  = (const float*)d_in[0];
  const int* mask = (const int*)d_in[1];
  const float* Wq = (const float*)d_in[2];
  const float* bq = (const float*)d_in[3];
  const float* Wk = (const float*)d_in[4];
  const float* bk = (const float*)d_in[5];
  const float* Wv = (const float*)d_in[6];
  const float* bv = (const float*)d_in[7];
  const float* Wo = (const float*)d_in[8];
  const float* bo = (const float*)d_in[9];
  float* out = (float*)d_out;
  (void)in_sizes; (void)n_in; (void)out_size; (void)ws_size;

  char* ws = (char*)d_ws;
  size_t off = 0;
  auto alloc = [&](size_t bytes){ void* p = ws + off; off += (bytes + 255) & ~(size_t)255; return p; };
  u16* xb    = (u16*)alloc((size_t)8192 * 1024 * 2);
  u16* WT    = (u16*)alloc((size_t)4 * 1024 * 1024 * 2);
  float* cosT = (float*)alloc((size_t)2048 * 32 * 4);
  float* sinT = (float*)alloc((size_t)2048 * 32 * 4);
  u16* Qr    = (u16*)alloc((size_t)8192 * 1024 * 2);
  u16* Kr    = (u16*)alloc((size_t)8192 * 1024 * 2);
  u16* Vt    = (u16*)alloc((size_t)8192 * 1024 * 2);
  u16* AO    = (u16*)alloc((size_t)8192 * 1024 * 2);

  rope_tab_k<<<dim3(256), dim3(256), 0, stream>>>(cosT, sinT);
  cvt_x_k<<<dim3(8192), dim3(256), 0, stream>>>(x, xb, 8192 * 1024);
  wt_cvt_k<<<dim3(32, 32, 4), dim3(32, 8), 0, stream>>>(Wq, Wk, Wv, Wo, WT);

  qkv_gemm_k<<<dim3(64, 24), dim3(256), 0, stream>>>(xb, WT, bq, bk, bv, cosT, sinT, Qr, Kr, Vt);

  attn_fwd_k<<<dim3(8, 64), dim3(512), 0, stream>>>(Qr, Kr, Vt, mask, AO);

  out_gemm_k<<<dim3(64, 8), dim3(256), 0, stream>>>(AO, WT + 3*1024*1024, bo, out);
}